// Round 19
// baseline (134.536 us; speedup 1.0000x reference)
//
#include <hip/hip_runtime.h>
#include <hip/hip_bf16.h>
#include <stdint.h>

typedef _Float16 f16x8_t __attribute__((ext_vector_type(8)));
typedef _Float16 f16x4_t __attribute__((ext_vector_type(4)));
typedef float    f32x4_t __attribute__((ext_vector_type(4)));

#define T_SEQ 2048
#define NH    16
#define HD    64
#define CDIM  1024
#define NTOK  4096          // B*T
#define QSCALE 0.18033688011112042f   // (1/sqrt(64)) * log2(e)
#define LOG2E  1.4426950408889634f

// ---------- async global->LDS, 16B per lane ----------
__device__ __forceinline__ void async_ld16(void* lds, const void* g) {
    __builtin_amdgcn_global_load_lds(
        (const __attribute__((address_space(1))) uint32_t*)g,
        (__attribute__((address_space(3))) uint32_t*)lds, 16, 0, 0);
}

// ---------- fused: fp32->fp16 converts (x, Wq,Wk,Wv,Wo) + mask-nonzero flag ----------
__global__ __launch_bounds__(256)
void prep_all(const float* __restrict__ x, const float* __restrict__ Wq,
              const float* __restrict__ Wk, const float* __restrict__ Wv,
              const float* __restrict__ Wo, const float* __restrict__ mask,
              _Float16* __restrict__ xh, _Float16* __restrict__ Wqkvh,
              _Float16* __restrict__ Woh, int* __restrict__ flag)
{
    const int XQ = NTOK * CDIM / 4;     // 1M float4
    const int WQ = CDIM * CDIM / 4;     // 256K float4
    int i = blockIdx.x * 256 + threadIdx.x;
    if (i < XQ + 4 * WQ) {
        const float* s; _Float16* d; int off;
        if (i < XQ) { s = x; d = xh; off = i; }
        else {
            int j = i - XQ; int w = j >> 18; off = j & (WQ - 1);
            s = (w == 0) ? Wq : (w == 1) ? Wk : (w == 2) ? Wv : Wo;
            d = (w == 3) ? Woh : Wqkvh + (size_t)w * CDIM * CDIM;
        }
        float4 v = ((const float4*)s)[off];
        f16x4_t h = {(_Float16)v.x, (_Float16)v.y, (_Float16)v.z, (_Float16)v.w};
        ((f16x4_t*)d)[off] = h;
    } else {
        int off = i - (XQ + 4 * WQ);
        float4 v = ((const float4*)mask)[off];
        if (v.x != 0.f || v.y != 0.f || v.z != 0.f || v.w != 0.f) atomicOr(flag, 1);
    }
}

// ---------- QKV GEMM: 256x256 block, BK=64, 8 waves (2Mx4N), phase-interleaved ----------
// C[cc][tok] = Wqkv[cc][K] * x[tok][K]^T, scatter Q (scaled) / K / V attn-chunked.
// LDS [2 dbuf][2 half][128 rows][64 halves] per matrix (128KB); chunk-XOR swizzle
// (read beats hit all 32 banks). Per K-tile: barrier A; issue kt+1 ht0 (db^1, whose
// readers finished in kt-1 => safe); vmcnt(2) (kt's 8 loads landed, ht0 in flight);
// barrier B (publishes all waves' waits); B-frags hoisted (8 reads); 4 phases each
// {stage 1 half-tile || 4 a-frag reads || 16 MFMA}. 24 reads / 64 MFMA per wave-tile.
__global__ __launch_bounds__(512, 2)
void gemm_qkv256(const _Float16* __restrict__ Ag, const _Float16* __restrict__ Bg,
                 const float* __restrict__ b0, const float* __restrict__ b1,
                 const float* __restrict__ b2,
                 _Float16* __restrict__ Qo, _Float16* __restrict__ Ko,
                 _Float16* __restrict__ Vto)
{
    __shared__ _Float16 sA[4][8192];   // [db*2+half][row 0..127][chunk 0..7][8]  64KB
    __shared__ _Float16 sB[4][8192];   // 64KB
    const int K = CDIM;
    const int tid  = threadIdx.x;
    const int lane = tid & 63, wv = tid >> 6;
    const int wr = wv >> 2, wc = wv & 3;           // 2M x 4N wave grid
    const int fr = lane & 15, fg = lane >> 4;
    const int bid = blockIdx.x;
    const int xcd = bid & 7, L = bid >> 3;         // 192 = 8 x 24
    const int a_blk = L % 12, b_blk = xcd * 2 + (L / 12);
    const int rowA0 = a_blk * 256, rowB0 = b_blk * 256;
    const int t8 = tid & 7, trow = tid >> 3;       // staging coords
    f32x4_t acc[8][4] = {};

#define STHT(ptr, blk0, half, ktv, db, sh) do {                                      \
        _Pragma("unroll")                                                            \
        for (int j_ = 0; j_ < 2; ++j_) {                                             \
            const int r_ = trow + j_ * 64;                                           \
            const int sc_ = t8 ^ (r_ & 7);                                           \
            async_ld16(&sh[(db) * 2 + (half)][j_ * 4096 + tid * 8],                  \
                       ptr + (size_t)((blk0) + (half) * 128 + r_) * K + (ktv) * 64 + sc_ * 8); \
        } } while (0)

    // prologue: stage K-tile 0 fully into db0
    STHT(Ag, rowA0, 0, 0, 0, sA);
    STHT(Ag, rowA0, 1, 0, 0, sA);
    STHT(Bg, rowB0, 0, 0, 0, sB);
    STHT(Bg, rowB0, 1, 0, 0, sB);

    const int NKT = K / 64;   // 16
    for (int kt = 0; kt < NKT; ++kt) {
        const int db = kt & 1;
        __builtin_amdgcn_s_barrier();            // A: all readers of db^1 (kt-1) done
        if (kt + 1 < NKT) {
            STHT(Ag, rowA0, 0, kt + 1, db ^ 1, sA);          // ht0
            asm volatile("s_waitcnt vmcnt(2)" ::: "memory"); // kt's 8 landed; ht0 in flight
        } else {
            asm volatile("s_waitcnt vmcnt(0)" ::: "memory");
        }
        __builtin_amdgcn_s_barrier();            // B: every wave's wait visible
        __builtin_amdgcn_sched_barrier(0);

        // hoist B fragments for this K-tile (8 reads)
        f16x8_t b[4][2];
#pragma unroll
        for (int ni = 0; ni < 4; ++ni)
#pragma unroll
            for (int ks = 0; ks < 2; ++ks) {
                const int rowin = ((wc & 1) * 64) + ni * 16 + fr;
                const int ch = (ks * 4 + fg) ^ (rowin & 7);
                b[ni][ks] = *(const f16x8_t*)&sB[db * 2 + (wc >> 1)][rowin * 64 + ch * 8];
            }
#pragma unroll
        for (int q = 0; q < 4; ++q) {
            if (kt + 1 < NKT) {
                if (q == 1)      STHT(Ag, rowA0, 1, kt + 1, db ^ 1, sA);
                else if (q == 2) STHT(Bg, rowB0, 0, kt + 1, db ^ 1, sB);
                else if (q == 3) STHT(Bg, rowB0, 1, kt + 1, db ^ 1, sB);
            }
            f16x8_t a[2][2];
#pragma unroll
            for (int m2 = 0; m2 < 2; ++m2)
#pragma unroll
                for (int ks = 0; ks < 2; ++ks) {
                    const int rowin = (2 * q + m2) * 16 + fr;
                    const int ch = (ks * 4 + fg) ^ (rowin & 7);
                    a[m2][ks] = *(const f16x8_t*)&sA[db * 2 + wr][rowin * 64 + ch * 8];
                }
            __builtin_amdgcn_s_setprio(1);
#pragma unroll
            for (int m2 = 0; m2 < 2; ++m2)
#pragma unroll
                for (int ni = 0; ni < 4; ++ni)
#pragma unroll
                    for (int ks = 0; ks < 2; ++ks)
                        acc[2 * q + m2][ni] = __builtin_amdgcn_mfma_f32_16x16x32_f16(
                            a[m2][ks], b[ni][ks], acc[2 * q + m2][ni], 0, 0, 0);
            __builtin_amdgcn_s_setprio(0);
        }
    }
#undef STHT

    // epilogue: cc = output channel (4 consecutive per lane), tok = fr-mapped
    const int which = a_blk >> 2;                  // 0=Q 1=K 2=V (256 | 1024)
    const float* bp = (which == 0) ? b0 : ((which == 1) ? b1 : b2);
#pragma unroll
    for (int mi = 0; mi < 8; ++mi) {
        const int cc = (rowA0 & 1023) + wr * 128 + mi * 16 + fg * 4;  // within 1024
        const float4 bv = *(const float4*)&bp[cc];
        const int h = cc >> 6, d0 = cc & 63;
#pragma unroll
        for (int ni = 0; ni < 4; ++ni) {
            const int tok = rowB0 + wc * 64 + ni * 16 + fr;
            const int bh = (tok >> 11) * NH + h, tt = tok & (T_SEQ - 1);
            const float v0 = acc[mi][ni][0] + bv.x, v1 = acc[mi][ni][1] + bv.y;
            const float v2 = acc[mi][ni][2] + bv.z, v3 = acc[mi][ni][3] + bv.w;
            if (which == 0) {
                f16x4_t hq = {(_Float16)(v0 * QSCALE), (_Float16)(v1 * QSCALE),
                              (_Float16)(v2 * QSCALE), (_Float16)(v3 * QSCALE)};
                *(f16x4_t*)&Qo[((size_t)bh * T_SEQ + tt) * HD + d0] = hq;
            } else if (which == 1) {   // K chunked: [tile][d>>3][t&63][d&7]
                f16x4_t hk = {(_Float16)v0, (_Float16)v1, (_Float16)v2, (_Float16)v3};
                *(f16x4_t*)&Ko[((size_t)bh * 32 + (tt >> 6)) * 4096 +
                               (d0 >> 3) * 512 + (tt & 63) * 8 + (d0 & 7)] = hk;
            } else {                   // V chunked: [tile][(t>>3)&7][d][t&7]
                const size_t vb_ = ((size_t)bh * 32 + (tt >> 6)) * 4096 +
                                   (size_t)((tt >> 3) & 7) * 512 + (tt & 7);
                Vto[vb_ + (d0 + 0) * 8] = (_Float16)v0;
                Vto[vb_ + (d0 + 1) * 8] = (_Float16)v1;
                Vto[vb_ + (d0 + 2) * 8] = (_Float16)v2;
                Vto[vb_ + (d0 + 3) * 8] = (_Float16)v3;
            }
        }
    }
}

// ---------- out-proj GEMM (r17): 128x128, 3-buf + issue-early + counted vmcnt ----------
__global__ __launch_bounds__(256)
void gemm_out(const _Float16* __restrict__ Ag, const _Float16* __restrict__ Bg,
              const float* __restrict__ b0, float* __restrict__ Fo)
{
    __shared__ _Float16 sA[3][128 * 32];
    __shared__ _Float16 sB[3][128 * 32];
    const int K = CDIM;
    const int tid  = threadIdx.x;
    const int lane = tid & 63, wv = tid >> 6;
    const int wr = wv >> 1, wc = wv & 1;
    const int bid = blockIdx.x;
    const int xcd = bid & 7, L = bid >> 3;
    const int sb = L & 31, st = L >> 5;
    const int rowA0 = (st * 8 + (sb & 7)) * 128;
    const int rowB0 = (xcd * 4 + (sb >> 3)) * 128;
    const int srow = lane >> 2;
    const int scol = (((lane & 3) ^ (srow & 3)) * 8);
    const int fr = lane & 15, fg = lane >> 4;
    const int rsw = (fg ^ (fr & 3)) * 8;
    f32x4_t acc[4][4] = {};

#define STAGE(buf, kk) do {                                                     \
        _Pragma("unroll")                                                       \
        for (int i_ = 0; i_ < 2; ++i_) {                                        \
            const int eoff = i_ * 2048 + wv * 512;                              \
            const int r_ = i_ * 64 + wv * 16 + srow;                            \
            async_ld16(&sA[buf][eoff], Ag + (size_t)(rowA0 + r_) * K + (kk) + scol); \
            async_ld16(&sB[buf][eoff], Bg + (size_t)(rowB0 + r_) * K + (kk) + scol); \
        } } while (0)

    STAGE(0, 0);
    int cur = 0;
    for (int k0 = 0; k0 < K; k0 += 32) {
        const int nxt = (cur == 2) ? 0 : cur + 1;
        if (k0 + 32 < K) {
            STAGE(nxt, k0 + 32);
            asm volatile("s_waitcnt vmcnt(4)" ::: "memory");
        } else {
            asm volatile("s_waitcnt vmcnt(0)" ::: "memory");
        }
        __builtin_amdgcn_s_barrier();
        __builtin_amdgcn_sched_barrier(0);
        f16x8_t a[4], b[4];
#pragma unroll
        for (int mi = 0; mi < 4; ++mi)
            a[mi] = *(const f16x8_t*)&sA[cur][(wr * 64 + mi * 16 + fr) * 32 + rsw];
#pragma unroll
        for (int ni = 0; ni < 4; ++ni)
            b[ni] = *(const f16x8_t*)&sB[cur][(wc * 64 + ni * 16 + fr) * 32 + rsw];
#pragma unroll
        for (int mi = 0; mi < 4; ++mi)
#pragma unroll
            for (int ni = 0; ni < 4; ++ni)
                acc[mi][ni] = __builtin_amdgcn_mfma_f32_16x16x32_f16(a[mi], b[ni], acc[mi][ni], 0, 0, 0);
        cur = nxt;
    }
#undef STAGE

#pragma unroll
    for (int mi = 0; mi < 4; ++mi) {
        const int cc = rowA0 + wr * 64 + mi * 16 + fg * 4;
        const float4 bv = *(const float4*)&b0[cc];
#pragma unroll
        for (int ni = 0; ni < 4; ++ni) {
            const int tok = rowB0 + wc * 64 + ni * 16 + fr;
            float4 ov = {acc[mi][ni][0] + bv.x, acc[mi][ni][1] + bv.y,
                         acc[mi][ni][2] + bv.z, acc[mi][ni][3] + bv.w};
            *(float4*)&Fo[(size_t)tok * CDIM + cc] = ov;
        }
    }
}

// ---------- flash attention (r17 verbatim): 16x16 MFMA, 8 waves, P in-register ----------
__global__ __launch_bounds__(512, 4)
void attn_f16(const _Float16* __restrict__ Q, const _Float16* __restrict__ Kc,
              const _Float16* __restrict__ Vc, const float* __restrict__ mask,
              const int* __restrict__ mflag, _Float16* __restrict__ AO)
{
    __shared__ __align__(16) _Float16 sK[3][4096];   // [8 dchunk][64 k][8], 3-buf
    __shared__ __align__(16) _Float16 sV[3][4096];   // [8 kchunk][64 d][8], 3-buf

    const int tid = threadIdx.x;
    const int lane = tid & 63, wv = tid >> 6;
    const int fr = lane & 15, fg = lane >> 4;
    const int bid = blockIdx.x;
    const int swz = (bid & 7) * 64 + (bid >> 3);     // bijective, 512 % 8 == 0
    const int qx = swz & 15, bh = swz >> 4;
    const int b = bh >> 4, h = bh & (NH - 1);
    const int q0 = qx * 128 + wv * 16;
    const _Float16* Qb  = Q  + (size_t)bh * T_SEQ * HD;
    const _Float16* Kbh = Kc + (size_t)bh * (T_SEQ * HD);
    const _Float16* Vbh = Vc + (size_t)bh * (T_SEQ * HD);
    const int soff = wv * 512 + lane * 8;   // halves; lane*16B contiguous

    f16x8_t qf[2];   // Q pre-scaled by 1/sqrt(D)*log2e
#pragma unroll
    for (int dc = 0; dc < 2; ++dc)
        qf[dc] = *(const f16x8_t*)&Qb[(size_t)(q0 + fr) * HD + dc * 32 + fg * 8];

    const f16x8_t ones = {(_Float16)1.f, (_Float16)1.f, (_Float16)1.f, (_Float16)1.f,
                          (_Float16)1.f, (_Float16)1.f, (_Float16)1.f, (_Float16)1.f};
    f32x4_t o[4] = {};                 // O[q=fg*4+r][d=df*16+fr]
    f32x4_t lacc = {};                 // l[q=fg*4+r] via ones-MFMA
    float m_run = -1e30f;              // max for q = fr (log2 domain)
    const int mf = mflag[0];

    async_ld16(&sK[0][wv * 512], Kbh + soff);
    async_ld16(&sV[0][wv * 512], Vbh + soff);
    int cur = 0;

    for (int t = 0; t < T_SEQ / 64; ++t) {
        const int nxt = (cur == 2) ? 0 : cur + 1;
        if (t + 1 < T_SEQ / 64) {
            async_ld16(&sK[nxt][wv * 512], Kbh + (size_t)(t + 1) * 4096 + soff);
            async_ld16(&sV[nxt][wv * 512], Vbh + (size_t)(t + 1) * 4096 + soff);
            asm volatile("s_waitcnt vmcnt(2)" ::: "memory");  // cur landed; next in flight
        } else {
            asm volatile("s_waitcnt vmcnt(0)" ::: "memory");
        }
        __builtin_amdgcn_s_barrier();                         // raw barrier: NO drain
        __builtin_amdgcn_sched_barrier(0);

        // ---- S^T = K * Q^T : lane holds S[k=kt*16+fg*4+r][q=fr] ----
        f32x4_t s[4];
        __builtin_amdgcn_s_setprio(1);
#pragma unroll
        for (int kt = 0; kt < 4; ++kt) {
            f16x8_t kf0 = *(const f16x8_t*)&sK[cur][fg * 512       + (kt * 16 + fr) * 8];
            f16x8_t kf1 = *(const f16x8_t*)&sK[cur][(4 + fg) * 512 + (kt * 16 + fr) * 8];
            f32x4_t z = {};
            z     = __builtin_amdgcn_mfma_f32_16x16x32_f16(kf0, qf[0], z, 0, 0, 0);
            s[kt] = __builtin_amdgcn_mfma_f32_16x16x32_f16(kf1, qf[1], z, 0, 0, 0);
        }
        __builtin_amdgcn_s_setprio(0);

        // hoist V fragment reads; LDS latency hides under softmax VALU
        f16x8_t vb[2][4];
#pragma unroll
        for (int kt2 = 0; kt2 < 2; ++kt2)
#pragma unroll
            for (int df = 0; df < 4; ++df)
                vb[kt2][df] = *(const f16x8_t*)&sV[cur][(kt2 * 4 + fg) * 512 + (df * 16 + fr) * 8];

        if (mf) {
            const float* mrow = mask + (size_t)(q0 + fr) * T_SEQ + t * 64;
#pragma unroll
            for (int kt = 0; kt < 4; ++kt)
#pragma unroll
                for (int r = 0; r < 4; ++r)
                    s[kt][r] += mrow[kt * 16 + fg * 4 + r] * LOG2E;
        }

        // ---- online softmax (log2 domain; max3 tree + 2 cross-lane steps) ----
        const float t0 = fmaxf(fmaxf(s[0][0], s[0][1]), s[0][2]);
        const float t1 = fmaxf(fmaxf(s[0][3], s[1][0]), s[1][1]);
        const float t2 = fmaxf(fmaxf(s[1][2], s[1][3]), s[2][0]);
        const float t3 = fmaxf(fmaxf(s[2][1], s[2][2]), s[2][3]);
        const float t4 = fmaxf(fmaxf(s[3][0], s[3][1]), s[3][2]);
        float tmax = fmaxf(fmaxf(fmaxf(t0, t1), fmaxf(t2, t3)), fmaxf(t4, s[3][3]));
        tmax = fmaxf(tmax, __shfl_xor(tmax, 16, 64));
        tmax = fmaxf(tmax, __shfl_xor(tmax, 32, 64));

        if (!__all(tmax <= m_run + 8.0f)) {           // defer-max (T13)
            const float mnew = fmaxf(m_run, tmax);
            const float sc = __builtin_amdgcn_exp2f(m_run - mnew);
            m_run = mnew;
            float scq[4];
#pragma unroll
            for (int r = 0; r < 4; ++r)
                scq[r] = __shfl(sc, fg * 4 + r, 64);
#pragma unroll
            for (int r = 0; r < 4; ++r) {
                lacc[r] *= scq[r];
#pragma unroll
                for (int df = 0; df < 4; ++df)
                    o[df][r] *= scq[r];
            }
        }

        // ---- P = exp2(S - m); pack to words u[kt][h] (k = kt*16 + fg*4 + 2h,+1) ----
        uint32_t U[4][2];
#pragma unroll
        for (int kt = 0; kt < 4; ++kt) {
            const float p0 = __builtin_amdgcn_exp2f(s[kt][0] - m_run);
            const float p1 = __builtin_amdgcn_exp2f(s[kt][1] - m_run);
            const float p2 = __builtin_amdgcn_exp2f(s[kt][2] - m_run);
            const float p3 = __builtin_amdgcn_exp2f(s[kt][3] - m_run);
            auto w0 = __builtin_amdgcn_cvt_pkrtz(p0, p1);
            auto w1 = __builtin_amdgcn_cvt_pkrtz(p2, p3);
            U[kt][0] = __builtin_bit_cast(uint32_t, w0);
            U[kt][1] = __builtin_bit_cast(uint32_t, w1);
        }

        // ---- P -> A-frags in-register: permlane32_swap then permlane16_swap ----
        f16x8_t pa[2];
#pragma unroll
        for (int kt2 = 0; kt2 < 2; ++kt2) {
            uint32_t w0, w1, w2, w3;
            {
                uint32_t y = U[2 * kt2][0], x = U[2 * kt2 + 1][0];
                asm("v_permlane32_swap_b32 %0, %1" : "+v"(y), "+v"(x));
                asm("v_permlane16_swap_b32 %0, %1" : "+v"(y), "+v"(x));
                w0 = y; w2 = x;
            }
            {
                uint32_t y = U[2 * kt2][1], x = U[2 * kt2 + 1][1];
                asm("v_permlane32_swap_b32 %0, %1" : "+v"(y), "+v"(x));
                asm("v_permlane16_swap_b32 %0, %1" : "+v"(y), "+v"(x));
                w1 = y; w3 = x;
            }
            union { uint32_t u4[4]; f16x8_t v; } uu;
            uu.u4[0] = w0; uu.u4[1] = w1; uu.u4[2] = w2; uu.u4[3] = w3;
            pa[kt2] = uu.v;
        }

        // ---- O += P * V ; l += P * 1 ----
        __builtin_amdgcn_s_setprio(1);
#pragma unroll
        for (int kt2 = 0; kt2 < 2; ++kt2) {
#pragma unroll
            for (int df = 0; df < 4; ++df)
                o[df] = __builtin_amdgcn_mfma_f32_16x16x32_f16(pa[kt2], vb[kt2][df], o[df], 0, 0, 0);
            lacc = __builtin_amdgcn_mfma_f32_16x16x32_f16(pa[kt2], ones, lacc, 0, 0, 0);
        }
        __builtin_amdgcn_s_setprio(0);
        cur = nxt;
    }

    // ---- epilogue: normalize, write (B,T,H*D) fp16 ----
#pragma unroll
    for (int r = 0; r < 4; ++r) {
        const float inv = 1.f / lacc[r];
        const size_t row = (size_t)(b * T_SEQ + q0 + fg * 4 + r);
#pragma unroll
        for (int df = 0; df < 4; ++df)
            AO[row * CDIM + h * HD + df * 16 + fr] = (_Float16)(o[df][r] * inv);
    }
}

extern "C" void kernel_launch(void* const* d_in, const int* in_sizes, int n_in,
                              void* d_out, int out_size, void* d_ws, size_t ws_size,
                              hipStream_t stream) {
    const float* x    = (const float*)d_in[0];
    const float* mask = (const float*)d_in[1];
    const float* Wq   = (const float*)d_in[2];
    const float* bq   = (const float*)d_in[3];
    const float* Wk   = (const float*)d_in[4];
    const float* bk   = (const float*)d_in[5];
    const float* Wv   = (const float*)d_in[6];
    const float* bv   = (const float*)d_in[7];
    const float* Wo   = (const float*)d_in[8];
    const float* bo   = (const float*)d_in[9];
    float* out = (float*)d_out;

    char* ws = (char*)d_ws;
    _Float16* xh    = (_Float16*)(ws);                    // 4096x1024  (8MB) -- reused as AO
    _Float16* Wqkvh = (_Float16*)(ws + (8u  << 20));      // 3072x1024  (6MB)
    _Float16* Woh   = (_Float16*)(ws + (14u << 20));      // 1024x1024  (2MB)
    _Float16* Qp    = (_Float16*)(ws + (16u << 20));      // (B,H,T,D)  (8MB)
    _Float16* Kc    = (_Float16*)(ws + (24u << 20));      // chunked    (8MB)
    _Float16* Vc    = (_Float16*)(ws + (32u << 20));      // chunked    (8MB)
    int* mflag      = (int*)(ws + (40u << 20));
    _Float16* AO    = xh;   // alias: x consumed by QKV GEMM before attn writes AO

    hipMemsetAsync(mflag, 0, 4, stream);
    prep_all<<<12288, 256, 0, stream>>>(x, Wq, Wk, Wv, Wo, mask, xh, Wqkvh, Woh, mflag);
    gemm_qkv256<<<192, 512, 0, stream>>>(Wqkvh, xh, bq, bk, bv, Qp, Kc, Vc);
    attn_f16<<<512, 512, 0, stream>>>(Qp, Kc, Vc, mask, mflag, AO);
    gemm_out<<<256, 256, 0, stream>>>(Woh, AO, bo, out);
}

// Round 20
// 125.392 us; speedup vs baseline: 1.0729x; 1.0729x over previous
//
#include <hip/hip_runtime.h>
#include <hip/hip_bf16.h>
#include <stdint.h>

typedef _Float16 f16x8_t __attribute__((ext_vector_type(8)));
typedef _Float16 f16x4_t __attribute__((ext_vector_type(4)));
typedef float    f32x4_t __attribute__((ext_vector_type(4)));

#define T_SEQ 2048
#define NH    16
#define HD    64
#define CDIM  1024
#define NTOK  4096          // B*T
#define QSCALE 0.18033688011112042f   // (1/sqrt(64)) * log2(e)
#define LOG2E  1.4426950408889634f

// ---------- async global->LDS, 16B per lane ----------
__device__ __forceinline__ void async_ld16(void* lds, const void* g) {
    __builtin_amdgcn_global_load_lds(
        (const __attribute__((address_space(1))) uint32_t*)g,
        (__attribute__((address_space(3))) uint32_t*)lds, 16, 0, 0);
}

// ---------- fused: fp32->fp16 converts (x, Wq,Wk,Wv,Wo) + mask-nonzero flag ----------
__global__ __launch_bounds__(256)
void prep_all(const float* __restrict__ x, const float* __restrict__ Wq,
              const float* __restrict__ Wk, const float* __restrict__ Wv,
              const float* __restrict__ Wo, const float* __restrict__ mask,
              _Float16* __restrict__ xh, _Float16* __restrict__ Wqkvh,
              _Float16* __restrict__ Woh, int* __restrict__ flag)
{
    const int XQ = NTOK * CDIM / 4;     // 1M float4
    const int WQ = CDIM * CDIM / 4;     // 256K float4
    int i = blockIdx.x * 256 + threadIdx.x;
    if (i < XQ + 4 * WQ) {
        const float* s; _Float16* d; int off;
        if (i < XQ) { s = x; d = xh; off = i; }
        else {
            int j = i - XQ; int w = j >> 18; off = j & (WQ - 1);
            s = (w == 0) ? Wq : (w == 1) ? Wk : (w == 2) ? Wv : Wo;
            d = (w == 3) ? Woh : Wqkvh + (size_t)w * CDIM * CDIM;
        }
        float4 v = ((const float4*)s)[off];
        f16x4_t h = {(_Float16)v.x, (_Float16)v.y, (_Float16)v.z, (_Float16)v.w};
        ((f16x4_t*)d)[off] = h;
    } else {
        int off = i - (XQ + 4 * WQ);
        float4 v = ((const float4*)mask)[off];
        if (v.x != 0.f || v.y != 0.f || v.z != 0.f || v.w != 0.f) atomicOr(flag, 1);
    }
}

// ---------- GEMM (C^T orientation): C[cc][tok] = A[cc][K] * B[tok][K]^T ----------
// Best-measured config (r17): 3-buf LDS + issue-early staging + counted vmcnt +
// raw s_barrier + chunk-XOR swizzle (2-way bank aliasing, free).
// MODE 0: QKV projection, scatter Q [bh][t][d] (scaled) and K/V attn-chunked, fp16
// MODE 1: out projection, fp32 [tok][cc] to d_out
template<int MODE>
__global__ __launch_bounds__(256)
void gemm_f16(const _Float16* __restrict__ Ag, const _Float16* __restrict__ Bg,
              const float* __restrict__ b0, const float* __restrict__ b1,
              const float* __restrict__ b2,
              _Float16* __restrict__ Qo, _Float16* __restrict__ Ko,
              _Float16* __restrict__ Vto, float* __restrict__ Fo)
{
    __shared__ _Float16 sA[3][128 * 32];   // 3-buf rotation, 48KB total -> 3 blocks/CU
    __shared__ _Float16 sB[3][128 * 32];
    const int K = CDIM;
    const int tid  = threadIdx.x;
    const int lane = tid & 63, wv = tid >> 6;
    const int wr = wv >> 1, wc = wv & 1;
    const int bid = blockIdx.x;
    const int xcd = bid & 7, L = bid >> 3;
    const int sb = L & 31, st = L >> 5;
    const int rowA0 = (st * 8 + (sb & 7)) * 128;
    const int rowB0 = (xcd * 4 + (sb >> 3)) * 128;
    const int srow = lane >> 2;                        // staging row within 16-row chunk
    const int scol = (((lane & 3) ^ (srow & 3)) * 8);  // XOR-swizzled chunk (same 64B line)
    const int fr = lane & 15, fg = lane >> 4;
    const int rsw = (fg ^ (fr & 3)) * 8;               // read-side chunk
    f32x4_t acc[4][4] = {};

#define STAGE(buf, kk) do {                                                     \
        _Pragma("unroll")                                                       \
        for (int i_ = 0; i_ < 2; ++i_) {                                        \
            const int eoff = i_ * 2048 + wv * 512;                              \
            const int r_ = i_ * 64 + wv * 16 + srow;                            \
            async_ld16(&sA[buf][eoff], Ag + (size_t)(rowA0 + r_) * K + (kk) + scol); \
            async_ld16(&sB[buf][eoff], Bg + (size_t)(rowB0 + r_) * K + (kk) + scol); \
        } } while (0)

    STAGE(0, 0);
    int cur = 0;
    for (int k0 = 0; k0 < K; k0 += 32) {
        const int nxt = (cur == 2) ? 0 : cur + 1;
        if (k0 + 32 < K) {
            STAGE(nxt, k0 + 32);
            asm volatile("s_waitcnt vmcnt(4)" ::: "memory");
        } else {
            asm volatile("s_waitcnt vmcnt(0)" ::: "memory");
        }
        __builtin_amdgcn_s_barrier();
        __builtin_amdgcn_sched_barrier(0);
        f16x8_t a[4], b[4];
#pragma unroll
        for (int mi = 0; mi < 4; ++mi)
            a[mi] = *(const f16x8_t*)&sA[cur][(wr * 64 + mi * 16 + fr) * 32 + rsw];
#pragma unroll
        for (int ni = 0; ni < 4; ++ni)
            b[ni] = *(const f16x8_t*)&sB[cur][(wc * 64 + ni * 16 + fr) * 32 + rsw];
#pragma unroll
        for (int mi = 0; mi < 4; ++mi)
#pragma unroll
            for (int ni = 0; ni < 4; ++ni)
                acc[mi][ni] = __builtin_amdgcn_mfma_f32_16x16x32_f16(a[mi], b[ni], acc[mi][ni], 0, 0, 0);
        cur = nxt;
    }
#undef STAGE

    if (MODE == 0) {
        const int which = rowA0 >> 10;
        const float* bp = (which == 0) ? b0 : ((which == 1) ? b1 : b2);
#pragma unroll
        for (int mi = 0; mi < 4; ++mi) {
            const int cc = (rowA0 & 1023) + wr * 64 + mi * 16 + fg * 4;
            const float4 bv = *(const float4*)&bp[cc];
            const int h = cc >> 6, d0 = cc & 63;
#pragma unroll
            for (int ni = 0; ni < 4; ++ni) {
                const int tok = rowB0 + wc * 64 + ni * 16 + fr;
                const int bh = (tok >> 11) * NH + h, tt = tok & (T_SEQ - 1);
                const float v0 = acc[mi][ni][0] + bv.x, v1 = acc[mi][ni][1] + bv.y;
                const float v2 = acc[mi][ni][2] + bv.z, v3 = acc[mi][ni][3] + bv.w;
                if (which == 0) {
                    f16x4_t hq = {(_Float16)(v0 * QSCALE), (_Float16)(v1 * QSCALE),
                                  (_Float16)(v2 * QSCALE), (_Float16)(v3 * QSCALE)};
                    *(f16x4_t*)&Qo[((size_t)bh * T_SEQ + tt) * HD + d0] = hq;
                } else if (which == 1) {   // K chunked: [tile][d>>3][t&63][d&7]
                    f16x4_t hk = {(_Float16)v0, (_Float16)v1, (_Float16)v2, (_Float16)v3};
                    *(f16x4_t*)&Ko[((size_t)bh * 32 + (tt >> 6)) * 4096 +
                                   (d0 >> 3) * 512 + (tt & 63) * 8 + (d0 & 7)] = hk;
                } else {                   // V chunked: [tile][(t>>3)&7][d][t&7]
                    const size_t vb_ = ((size_t)bh * 32 + (tt >> 6)) * 4096 +
                                       (size_t)((tt >> 3) & 7) * 512 + (tt & 7);
                    Vto[vb_ + (d0 + 0) * 8] = (_Float16)v0;
                    Vto[vb_ + (d0 + 1) * 8] = (_Float16)v1;
                    Vto[vb_ + (d0 + 2) * 8] = (_Float16)v2;
                    Vto[vb_ + (d0 + 3) * 8] = (_Float16)v3;
                }
            }
        }
    } else {
#pragma unroll
        for (int mi = 0; mi < 4; ++mi) {
            const int cc = rowA0 + wr * 64 + mi * 16 + fg * 4;
            const float4 bv = *(const float4*)&b0[cc];
#pragma unroll
            for (int ni = 0; ni < 4; ++ni) {
                const int tok = rowB0 + wc * 64 + ni * 16 + fr;
                float4 ov = {acc[mi][ni][0] + bv.x, acc[mi][ni][1] + bv.y,
                             acc[mi][ni][2] + bv.z, acc[mi][ni][3] + bv.w};
                *(float4*)&Fo[(size_t)tok * CDIM + cc] = ov;
            }
        }
    }
}

// ---------- flash attention: 16x16 MFMA, 8 waves, P fully in-register (r17) ----------
// 3-buf + issue-early + counted vmcnt + raw barrier; P -> A-frags via cvt_pkrtz +
// permlane32_swap/permlane16_swap (no LDS round-trip); l via ones-MFMA.
__global__ __launch_bounds__(512, 4)
void attn_f16(const _Float16* __restrict__ Q, const _Float16* __restrict__ Kc,
              const _Float16* __restrict__ Vc, const float* __restrict__ mask,
              const int* __restrict__ mflag, _Float16* __restrict__ AO)
{
    __shared__ __align__(16) _Float16 sK[3][4096];   // [8 dchunk][64 k][8], 3-buf
    __shared__ __align__(16) _Float16 sV[3][4096];   // [8 kchunk][64 d][8], 3-buf

    const int tid = threadIdx.x;
    const int lane = tid & 63, wv = tid >> 6;
    const int fr = lane & 15, fg = lane >> 4;
    const int bid = blockIdx.x;
    const int swz = (bid & 7) * 64 + (bid >> 3);     // bijective, 512 % 8 == 0
    const int qx = swz & 15, bh = swz >> 4;
    const int b = bh >> 4, h = bh & (NH - 1);
    const int q0 = qx * 128 + wv * 16;
    const _Float16* Qb  = Q  + (size_t)bh * T_SEQ * HD;
    const _Float16* Kbh = Kc + (size_t)bh * (T_SEQ * HD);
    const _Float16* Vbh = Vc + (size_t)bh * (T_SEQ * HD);
    const int soff = wv * 512 + lane * 8;   // halves; lane*16B contiguous

    f16x8_t qf[2];   // Q pre-scaled by 1/sqrt(D)*log2e
#pragma unroll
    for (int dc = 0; dc < 2; ++dc)
        qf[dc] = *(const f16x8_t*)&Qb[(size_t)(q0 + fr) * HD + dc * 32 + fg * 8];

    const f16x8_t ones = {(_Float16)1.f, (_Float16)1.f, (_Float16)1.f, (_Float16)1.f,
                          (_Float16)1.f, (_Float16)1.f, (_Float16)1.f, (_Float16)1.f};
    f32x4_t o[4] = {};                 // O[q=fg*4+r][d=df*16+fr]
    f32x4_t lacc = {};                 // l[q=fg*4+r] via ones-MFMA
    float m_run = -1e30f;              // max for q = fr (log2 domain)
    const int mf = mflag[0];

    async_ld16(&sK[0][wv * 512], Kbh + soff);
    async_ld16(&sV[0][wv * 512], Vbh + soff);
    int cur = 0;

    for (int t = 0; t < T_SEQ / 64; ++t) {
        const int nxt = (cur == 2) ? 0 : cur + 1;
        if (t + 1 < T_SEQ / 64) {
            async_ld16(&sK[nxt][wv * 512], Kbh + (size_t)(t + 1) * 4096 + soff);
            async_ld16(&sV[nxt][wv * 512], Vbh + (size_t)(t + 1) * 4096 + soff);
            asm volatile("s_waitcnt vmcnt(2)" ::: "memory");  // cur landed; next in flight
        } else {
            asm volatile("s_waitcnt vmcnt(0)" ::: "memory");
        }
        __builtin_amdgcn_s_barrier();                         // raw barrier: NO drain
        __builtin_amdgcn_sched_barrier(0);

        // ---- S^T = K * Q^T : lane holds S[k=kt*16+fg*4+r][q=fr] ----
        f32x4_t s[4];
        __builtin_amdgcn_s_setprio(1);
#pragma unroll
        for (int kt = 0; kt < 4; ++kt) {
            f16x8_t kf0 = *(const f16x8_t*)&sK[cur][fg * 512       + (kt * 16 + fr) * 8];
            f16x8_t kf1 = *(const f16x8_t*)&sK[cur][(4 + fg) * 512 + (kt * 16 + fr) * 8];
            f32x4_t z = {};
            z     = __builtin_amdgcn_mfma_f32_16x16x32_f16(kf0, qf[0], z, 0, 0, 0);
            s[kt] = __builtin_amdgcn_mfma_f32_16x16x32_f16(kf1, qf[1], z, 0, 0, 0);
        }
        __builtin_amdgcn_s_setprio(0);

        // hoist V fragment reads; LDS latency hides under softmax VALU
        f16x8_t vb[2][4];
#pragma unroll
        for (int kt2 = 0; kt2 < 2; ++kt2)
#pragma unroll
            for (int df = 0; df < 4; ++df)
                vb[kt2][df] = *(const f16x8_t*)&sV[cur][(kt2 * 4 + fg) * 512 + (df * 16 + fr) * 8];

        if (mf) {
            const float* mrow = mask + (size_t)(q0 + fr) * T_SEQ + t * 64;
#pragma unroll
            for (int kt = 0; kt < 4; ++kt)
#pragma unroll
                for (int r = 0; r < 4; ++r)
                    s[kt][r] += mrow[kt * 16 + fg * 4 + r] * LOG2E;
        }

        // ---- online softmax (log2 domain; max3 tree + 2 cross-lane steps) ----
        const float t0 = fmaxf(fmaxf(s[0][0], s[0][1]), s[0][2]);
        const float t1 = fmaxf(fmaxf(s[0][3], s[1][0]), s[1][1]);
        const float t2 = fmaxf(fmaxf(s[1][2], s[1][3]), s[2][0]);
        const float t3 = fmaxf(fmaxf(s[2][1], s[2][2]), s[2][3]);
        const float t4 = fmaxf(fmaxf(s[3][0], s[3][1]), s[3][2]);
        float tmax = fmaxf(fmaxf(fmaxf(t0, t1), fmaxf(t2, t3)), fmaxf(t4, s[3][3]));
        tmax = fmaxf(tmax, __shfl_xor(tmax, 16, 64));
        tmax = fmaxf(tmax, __shfl_xor(tmax, 32, 64));

        if (!__all(tmax <= m_run + 8.0f)) {           // defer-max (T13)
            const float mnew = fmaxf(m_run, tmax);
            const float sc = __builtin_amdgcn_exp2f(m_run - mnew);
            m_run = mnew;
            float scq[4];
#pragma unroll
            for (int r = 0; r < 4; ++r)
                scq[r] = __shfl(sc, fg * 4 + r, 64);
#pragma unroll
            for (int r = 0; r < 4; ++r) {
                lacc[r] *= scq[r];
#pragma unroll
                for (int df = 0; df < 4; ++df)
                    o[df][r] *= scq[r];
            }
        }

        // ---- P = exp2(S - m); pack to words u[kt][h] (k = kt*16 + fg*4 + 2h,+1) ----
        uint32_t U[4][2];
#pragma unroll
        for (int kt = 0; kt < 4; ++kt) {
            const float p0 = __builtin_amdgcn_exp2f(s[kt][0] - m_run);
            const float p1 = __builtin_amdgcn_exp2f(s[kt][1] - m_run);
            const float p2 = __builtin_amdgcn_exp2f(s[kt][2] - m_run);
            const float p3 = __builtin_amdgcn_exp2f(s[kt][3] - m_run);
            auto w0 = __builtin_amdgcn_cvt_pkrtz(p0, p1);
            auto w1 = __builtin_amdgcn_cvt_pkrtz(p2, p3);
            U[kt][0] = __builtin_bit_cast(uint32_t, w0);
            U[kt][1] = __builtin_bit_cast(uint32_t, w1);
        }

        // ---- P -> A-frags in-register: permlane32_swap then permlane16_swap ----
        f16x8_t pa[2];
#pragma unroll
        for (int kt2 = 0; kt2 < 2; ++kt2) {
            uint32_t w0, w1, w2, w3;
            {
                uint32_t y = U[2 * kt2][0], x = U[2 * kt2 + 1][0];
                asm("v_permlane32_swap_b32 %0, %1" : "+v"(y), "+v"(x));
                asm("v_permlane16_swap_b32 %0, %1" : "+v"(y), "+v"(x));
                w0 = y; w2 = x;
            }
            {
                uint32_t y = U[2 * kt2][1], x = U[2 * kt2 + 1][1];
                asm("v_permlane32_swap_b32 %0, %1" : "+v"(y), "+v"(x));
                asm("v_permlane16_swap_b32 %0, %1" : "+v"(y), "+v"(x));
                w1 = y; w3 = x;
            }
            union { uint32_t u4[4]; f16x8_t v; } uu;
            uu.u4[0] = w0; uu.u4[1] = w1; uu.u4[2] = w2; uu.u4[3] = w3;
            pa[kt2] = uu.v;
        }

        // ---- O += P * V ; l += P * 1 ----
        __builtin_amdgcn_s_setprio(1);
#pragma unroll
        for (int kt2 = 0; kt2 < 2; ++kt2) {
#pragma unroll
            for (int df = 0; df < 4; ++df)
                o[df] = __builtin_amdgcn_mfma_f32_16x16x32_f16(pa[kt2], vb[kt2][df], o[df], 0, 0, 0);
            lacc = __builtin_amdgcn_mfma_f32_16x16x32_f16(pa[kt2], ones, lacc, 0, 0, 0);
        }
        __builtin_amdgcn_s_setprio(0);
        cur = nxt;
    }

    // ---- epilogue: normalize, write (B,T,H*D) fp16 ----
#pragma unroll
    for (int r = 0; r < 4; ++r) {
        const float inv = 1.f / lacc[r];
        const size_t row = (size_t)(b * T_SEQ + q0 + fg * 4 + r);
#pragma unroll
        for (int df = 0; df < 4; ++df)
            AO[row * CDIM + h * HD + df * 16 + fr] = (_Float16)(o[df][r] * inv);
    }
}

extern "C" void kernel_launch(void* const* d_in, const int* in_sizes, int n_in,
                              void* d_out, int out_size, void* d_ws, size_t ws_size,
                              hipStream_t stream) {
    const float* x    = (const float*)d_in[0];
    const float* mask = (const float*)d_in[1];
    const float* Wq   = (const float*)d_in[2];
    const float* bq   = (const float*)d_in[3];
    const float* Wk   = (const float*)d_in[4];
    const float* bk   = (const float*)d_in[5];
    const float* Wv   = (const float*)d_in[6];
    const float* bv   = (const float*)d_in[7];
    const float* Wo   = (const float*)d_in[8];
    const float* bo   = (const float*)d_in[9];
    float* out = (float*)d_out;

    char* ws = (char*)d_ws;
    _Float16* xh    = (_Float16*)(ws);                    // 4096x1024  (8MB) -- reused as AO
    _Float16* Wqkvh = (_Float16*)(ws + (8u  << 20));      // 3072x1024  (6MB)
    _Float16* Woh   = (_Float16*)(ws + (14u << 20));      // 1024x1024  (2MB)
    _Float16* Qp    = (_Float16*)(ws + (16u << 20));      // (B,H,T,D)  (8MB)
    _Float16* Kc    = (_Float16*)(ws + (24u << 20));      // chunked    (8MB)
    _Float16* Vc    = (_Float16*)(ws + (32u << 20));      // chunked    (8MB)
    int* mflag      = (int*)(ws + (40u << 20));
    _Float16* AO    = xh;   // alias: x consumed by QKV GEMM before attn writes AO

    hipMemsetAsync(mflag, 0, 4, stream);
    prep_all<<<12288, 256, 0, stream>>>(x, Wq, Wk, Wv, Wo, mask, xh, Wqkvh, Woh, mflag);
    gemm_f16<0><<<768, 256, 0, stream>>>(Wqkvh, xh, bq, bk, bv, Qp, Kc, Vc, nullptr);
    attn_f16<<<512, 512, 0, stream>>>(Qp, Kc, Vc, mask, mflag, AO);
    gemm_f16<1><<<256, 256, 0, stream>>>(Woh, AO, bo, nullptr, nullptr,
                                         nullptr, nullptr, nullptr, out);
}